// Round 2
// baseline (356.055 us; speedup 1.0000x reference)
//
#include <hip/hip_runtime.h>

#define B_  64
#define D_  4096
#define S_  128
#define N_  256
#define KC_ 4
#define KPB (D_ / KC_)   // 1024 K per gram block
#define BK  64           // K-chunk staged in LDS
#define NCH (KPB / BK)   // 16 chunks

using short8   = __attribute__((ext_vector_type(8)))  short;
using floatx16 = __attribute__((ext_vector_type(16))) float;

__device__ __forceinline__ unsigned int f2bf(float f) {
  unsigned int u = __builtin_bit_cast(unsigned int, f);
  return (u + 0x7FFFu + ((u >> 16) & 1u)) >> 16;   // round-to-nearest-even
}

// gram[b][n][m] += sum over this block's K-range of x[b][n][k]*x[b][m][k]
// x[b][n][k] = source[b][k][n] (n<128) or target[b][k][n-128]
// Double-buffered LDS + register prefetch: loads for chunk ch+1 issue before
// the MFMA phase of chunk ch; one barrier per chunk.
__global__ __launch_bounds__(1024, 4) void k_gram(
    const float* __restrict__ src, const float* __restrict__ tgt,
    float* __restrict__ gram) {
  // [buf][n][k] bf16, row = 64 ushorts (128 B); 16B granule g stored at
  // (g ^ (n&7)) -> bank-uniform b128 reads AND writes.
  __shared__ unsigned short lds[2 * N_ * BK];  // 64 KB
  const int kc  = blockIdx.x;
  const int b   = blockIdx.y;
  const int tid = threadIdx.x;
  const int l   = tid & 63;
  const int w   = tid >> 6;            // wave 0..15
  const int tr  = w >> 2, tc = w & 3;  // 4x4 grid of 64x64 wave tiles

  // staging role: thread owns column n_s, granules g4 and g4+4 (8 k each)
  const int n_s = tid & 255;
  const int g4  = tid >> 8;            // 0..3
  const float* colbase = (n_s < S_)
      ? (src + (size_t)b * D_ * S_ + n_s)
      : (tgt + (size_t)b * D_ * S_ + (n_s - S_));
  const float* pA = colbase + (size_t)(kc * KPB + g4 * 8) * S_;

  float ld[16];
  floatx16 acc[2][2];
  #pragma unroll
  for (int i = 0; i < 2; i++)
    #pragma unroll
    for (int j = 0; j < 2; j++)
      #pragma unroll
      for (int r = 0; r < 16; r++) acc[i][j][r] = 0.f;

  const int lm = l & 31;
  const int lk = l >> 5;               // 0/1
  const int am = tr * 64 + lm;         // A-frag row (sub adds 32)
  const int bm = tc * 64 + lm;         // B-frag col

  #define LOADCH(ch)                                                   \
    do {                                                               \
      const float* q = pA + (size_t)(ch) * BK * S_;                    \
      _Pragma("unroll")                                                \
      for (int j = 0; j < 8; j++) {                                    \
        ld[j]     = q[j * S_];                                         \
        ld[8 + j] = q[(32 + j) * S_];                                  \
      }                                                                \
    } while (0)

  #define WRITECH(buf)                                                 \
    do {                                                               \
      uint4 wa, wb;                                                    \
      wa.x = f2bf(ld[0])  | (f2bf(ld[1])  << 16);                      \
      wa.y = f2bf(ld[2])  | (f2bf(ld[3])  << 16);                      \
      wa.z = f2bf(ld[4])  | (f2bf(ld[5])  << 16);                      \
      wa.w = f2bf(ld[6])  | (f2bf(ld[7])  << 16);                      \
      wb.x = f2bf(ld[8])  | (f2bf(ld[9])  << 16);                      \
      wb.y = f2bf(ld[10]) | (f2bf(ld[11]) << 16);                      \
      wb.z = f2bf(ld[12]) | (f2bf(ld[13]) << 16);                      \
      wb.w = f2bf(ld[14]) | (f2bf(ld[15]) << 16);                      \
      const int r0 = (buf) * (N_ * BK) + n_s * BK;                     \
      *(uint4*)&lds[r0 + (((g4)     ^ (n_s & 7)) << 3)] = wa;          \
      *(uint4*)&lds[r0 + (((g4 + 4) ^ (n_s & 7)) << 3)] = wb;          \
    } while (0)

  #define MFMACH(buf)                                                  \
    do {                                                               \
      const unsigned short* L = &lds[(buf) * (N_ * BK)];               \
      _Pragma("unroll")                                                \
      for (int ks = 0; ks < 4; ks++) {                                 \
        const int g = ks * 2 + lk;                                     \
        short8 a0 = *(const short8*)&L[(am)      * 64 + ((g ^ ((am)      & 7)) << 3)]; \
        short8 a1 = *(const short8*)&L[(am + 32) * 64 + ((g ^ ((am + 32) & 7)) << 3)]; \
        short8 b0 = *(const short8*)&L[(bm)      * 64 + ((g ^ ((bm)      & 7)) << 3)]; \
        short8 b1 = *(const short8*)&L[(bm + 32) * 64 + ((g ^ ((bm + 32) & 7)) << 3)]; \
        acc[0][0] = __builtin_amdgcn_mfma_f32_32x32x16_bf16(a0, b0, acc[0][0], 0, 0, 0); \
        acc[0][1] = __builtin_amdgcn_mfma_f32_32x32x16_bf16(a0, b1, acc[0][1], 0, 0, 0); \
        acc[1][0] = __builtin_amdgcn_mfma_f32_32x32x16_bf16(a1, b0, acc[1][0], 0, 0, 0); \
        acc[1][1] = __builtin_amdgcn_mfma_f32_32x32x16_bf16(a1, b1, acc[1][1], 0, 0, 0); \
      }                                                                \
    } while (0)

  LOADCH(0);
  WRITECH(0);
  __syncthreads();
  for (int ch = 0; ch < NCH - 1; ch++) {
    LOADCH(ch + 1);          // global loads fly during MFMA below
    MFMACH(ch & 1);
    WRITECH((ch + 1) & 1);   // vmcnt wait happens here
    __syncthreads();
  }
  MFMACH((NCH - 1) & 1);

  // epilogue: combine K-split partials via device-scope atomics
  float* gb = gram + (size_t)b * N_ * N_;
  #pragma unroll
  for (int i = 0; i < 2; i++)
    #pragma unroll
    for (int j = 0; j < 2; j++)
      #pragma unroll
      for (int r = 0; r < 16; r++) {
        const int row = (r & 3) + 8 * (r >> 2) + 4 * lk;  // verified C/D layout
        const int col = l & 31;
        const int nr = tr * 64 + i * 32 + row;
        const int nc = tc * 64 + j * 32 + col;
        atomicAdd(&gb[nr * N_ + nc], acc[i][j][r]);
      }
  #undef LOADCH
  #undef WRITECH
  #undef MFMACH
}

// Fused bandwidth + exp-reduce: one block per batch. Each thread holds 64
// gram values in registers; phase 1 computes bw from total+diag; phase 2
// does the 5-kernel exp sum with quadrant signs.
__global__ __launch_bounds__(1024, 4) void k_bwexp(
    const float* __restrict__ gram, float* __restrict__ out) {
  __shared__ float sq[N_];
  __shared__ float red[16];
  __shared__ float bws;
  const int b  = blockIdx.x;
  const int t  = threadIdx.x;          // 1024
  const int c  = t & 255;              // column
  const int rg = t >> 8;               // row group 0..3 (64 rows each)
  const float* gb = gram + (size_t)b * N_ * N_;

  float g[64];
  #pragma unroll
  for (int i = 0; i < 64; i++) g[i] = gb[(rg * 64 + i) * N_ + c];

  // diagonal -> sq[]
  if ((c >> 6) == rg) sq[c] = g[c & 63];

  float tot = 0.f;
  #pragma unroll
  for (int i = 0; i < 64; i++) tot += g[i];
  for (int off = 32; off; off >>= 1) tot += __shfl_down(tot, off);
  if ((t & 63) == 0) red[t >> 6] = tot;
  __syncthreads();

  if (t < 64) {
    float d = sq[t] + sq[t + 64] + sq[t + 128] + sq[t + 192];
    for (int off = 32; off; off >>= 1) d += __shfl_down(d, off);
    if (t == 0) {
      float T = 0.f;
      #pragma unroll
      for (int i = 0; i < 16; i++) T += red[i];
      float SL2 = 2.f * (float)N_ * d - 2.f * T;
      bws = SL2 / (float)(N_ * N_ - N_) * 0.25f;  // / kernel_mul^(num//2)
    }
  }
  __syncthreads();

  const float bwv = bws;
  float nb[5];
  #pragma unroll
  for (int k = 0; k < 5; k++)
    nb[k] = -1.4426950408889634f / (bwv * (float)(1 << k));
  const float sqc = sq[c];
  const float sgn = ((rg < 2) == (c < S_)) ? 1.f : -1.f;  // quadrant sign
  float accv = 0.f;
  #pragma unroll
  for (int i = 0; i < 64; i++) {
    const float L2 = sq[rg * 64 + i] + sqc - 2.f * g[i];
    float s = 0.f;
    #pragma unroll
    for (int k = 0; k < 5; k++) s += exp2f(L2 * nb[k]);
    accv += s;
  }
  accv *= sgn;
  for (int off = 32; off; off >>= 1) accv += __shfl_down(accv, off);
  __syncthreads();  // red[] reuse safe
  if ((t & 63) == 0) red[t >> 6] = accv;
  __syncthreads();
  if (t == 0) {
    float s = 0.f;
    #pragma unroll
    for (int i = 0; i < 16; i++) s += red[i];
    atomicAdd(out, s * (1.0f / (64.f * 16384.f)));  // / (B * S*S)
  }
}

extern "C" void kernel_launch(void* const* d_in, const int* in_sizes, int n_in,
                              void* d_out, int out_size, void* d_ws, size_t ws_size,
                              hipStream_t stream) {
  const float* src = (const float*)d_in[0];
  const float* tgt = (const float*)d_in[1];
  const size_t gram_bytes = (size_t)B_ * N_ * N_ * sizeof(float);  // 16.8 MB
  float* gram = (float*)d_ws;
  hipMemsetAsync(gram, 0, gram_bytes, stream);
  hipMemsetAsync(d_out, 0, sizeof(float), stream);
  k_gram<<<dim3(KC_, B_), 1024, 0, stream>>>(src, tgt, gram);
  k_bwexp<<<B_, 1024, 0, stream>>>(gram, (float*)d_out);
}

// Round 3
// 317.707 us; speedup vs baseline: 1.1207x; 1.1207x over previous
//
#include <hip/hip_runtime.h>

#define B_  64
#define D_  4096
#define S_  128
#define N_  256
#define KC_ 4
#define KPB (D_ / KC_)   // 1024 K per gram block
#define BK  64           // K-chunk staged in LDS
#define NCH (KPB / BK)   // 16 chunks
#define TILE_ (N_ * N_)  // 65536 elements per partial tile

using short8   = __attribute__((ext_vector_type(8)))  short;
using floatx16 = __attribute__((ext_vector_type(16))) float;

__device__ __forceinline__ unsigned int f2bf(float f) {
  unsigned int u = __builtin_bit_cast(unsigned int, f);
  return (u + 0x7FFFu + ((u >> 16) & 1u)) >> 16;   // round-to-nearest-even
}

// partial[kc][b][n][m] = sum over K-range kc of x[b][n][k]*x[b][m][k]
// x[b][n][k] = source[b][k][n] (n<128) or target[b][k][n-128]
// Plain stores (no atomics, no zero-init needed — every element written).
__global__ __launch_bounds__(1024, 4) void k_gram(
    const float* __restrict__ src, const float* __restrict__ tgt,
    float* __restrict__ partial) {
  // [buf][n][k] bf16, row = 64 ushorts (128 B); 16B granule g stored at
  // (g ^ (n&7)) -> bank-uniform b128 reads AND writes.
  __shared__ unsigned short lds[2 * N_ * BK];  // 64 KB
  const int kc  = blockIdx.x;
  const int b   = blockIdx.y;
  const int tid = threadIdx.x;
  const int l   = tid & 63;
  const int w   = tid >> 6;            // wave 0..15
  const int tr  = w >> 2, tc = w & 3;  // 4x4 grid of 64x64 wave tiles

  // staging role: thread owns column n_s, granules g4 and g4+4 (8 k each)
  const int n_s = tid & 255;
  const int g4  = tid >> 8;            // 0..3
  const float* colbase = (n_s < S_)
      ? (src + (size_t)b * D_ * S_ + n_s)
      : (tgt + (size_t)b * D_ * S_ + (n_s - S_));
  const float* pA = colbase + (size_t)(kc * KPB + g4 * 8) * S_;

  float ld[16];
  floatx16 acc[2][2];
  #pragma unroll
  for (int i = 0; i < 2; i++)
    #pragma unroll
    for (int j = 0; j < 2; j++)
      #pragma unroll
      for (int r = 0; r < 16; r++) acc[i][j][r] = 0.f;

  const int lm = l & 31;
  const int lk = l >> 5;               // 0/1
  const int am = tr * 64 + lm;         // A-frag row (sub adds 32)
  const int bm = tc * 64 + lm;         // B-frag col

  #define LOADCH(ch)                                                   \
    do {                                                               \
      const float* q = pA + (size_t)(ch) * BK * S_;                    \
      _Pragma("unroll")                                                \
      for (int j = 0; j < 8; j++) {                                    \
        ld[j]     = q[j * S_];                                         \
        ld[8 + j] = q[(32 + j) * S_];                                  \
      }                                                                \
    } while (0)

  #define WRITECH(buf)                                                 \
    do {                                                               \
      uint4 wa, wb;                                                    \
      wa.x = f2bf(ld[0])  | (f2bf(ld[1])  << 16);                      \
      wa.y = f2bf(ld[2])  | (f2bf(ld[3])  << 16);                      \
      wa.z = f2bf(ld[4])  | (f2bf(ld[5])  << 16);                      \
      wa.w = f2bf(ld[6])  | (f2bf(ld[7])  << 16);                      \
      wb.x = f2bf(ld[8])  | (f2bf(ld[9])  << 16);                      \
      wb.y = f2bf(ld[10]) | (f2bf(ld[11]) << 16);                      \
      wb.z = f2bf(ld[12]) | (f2bf(ld[13]) << 16);                      \
      wb.w = f2bf(ld[14]) | (f2bf(ld[15]) << 16);                      \
      const int r0 = (buf) * (N_ * BK) + n_s * BK;                     \
      *(uint4*)&lds[r0 + (((g4)     ^ (n_s & 7)) << 3)] = wa;          \
      *(uint4*)&lds[r0 + (((g4 + 4) ^ (n_s & 7)) << 3)] = wb;          \
    } while (0)

  #define MFMACH(buf)                                                  \
    do {                                                               \
      const unsigned short* L = &lds[(buf) * (N_ * BK)];               \
      _Pragma("unroll")                                                \
      for (int ks = 0; ks < 4; ks++) {                                 \
        const int g = ks * 2 + lk;                                     \
        short8 a0 = *(const short8*)&L[(am)      * 64 + ((g ^ ((am)      & 7)) << 3)]; \
        short8 a1 = *(const short8*)&L[(am + 32) * 64 + ((g ^ ((am + 32) & 7)) << 3)]; \
        short8 b0 = *(const short8*)&L[(bm)      * 64 + ((g ^ ((bm)      & 7)) << 3)]; \
        short8 b1 = *(const short8*)&L[(bm + 32) * 64 + ((g ^ ((bm + 32) & 7)) << 3)]; \
        acc[0][0] = __builtin_amdgcn_mfma_f32_32x32x16_bf16(a0, b0, acc[0][0], 0, 0, 0); \
        acc[0][1] = __builtin_amdgcn_mfma_f32_32x32x16_bf16(a0, b1, acc[0][1], 0, 0, 0); \
        acc[1][0] = __builtin_amdgcn_mfma_f32_32x32x16_bf16(a1, b0, acc[1][0], 0, 0, 0); \
        acc[1][1] = __builtin_amdgcn_mfma_f32_32x32x16_bf16(a1, b1, acc[1][1], 0, 0, 0); \
      }                                                                \
    } while (0)

  LOADCH(0);
  WRITECH(0);
  __syncthreads();
  for (int ch = 0; ch < NCH - 1; ch++) {
    LOADCH(ch + 1);          // global loads fly during MFMA below
    MFMACH(ch & 1);
    WRITECH((ch + 1) & 1);   // vmcnt wait happens here
    __syncthreads();
  }
  MFMACH((NCH - 1) & 1);

  // epilogue: plain stores into this block's private partial tile
  float* gb = partial + ((size_t)kc * B_ + b) * TILE_;
  #pragma unroll
  for (int i = 0; i < 2; i++)
    #pragma unroll
    for (int j = 0; j < 2; j++)
      #pragma unroll
      for (int r = 0; r < 16; r++) {
        const int row = (r & 3) + 8 * (r >> 2) + 4 * lk;  // verified C/D layout
        const int col = l & 31;
        const int nr = tr * 64 + i * 32 + row;
        const int nc = tc * 64 + j * 32 + col;
        gb[nr * N_ + nc] = acc[i][j][r];
      }
  #undef LOADCH
  #undef WRITECH
  #undef MFMACH
}

// Per-partial reduction: tot[b] += sum(partial tile), sq[b][c] += diag contrib.
// Tiny atomic volume (1 + 256 per block).
__global__ __launch_bounds__(1024, 4) void k_stat(
    const float* __restrict__ partial, float* __restrict__ tot,
    float* __restrict__ sq) {
  __shared__ float red[16];
  const int kc = blockIdx.x & 3;
  const int b  = blockIdx.x >> 2;
  const int t  = threadIdx.x;          // 1024
  const int c  = t & 255;
  const int rg = t >> 8;               // 64-row group
  const float* gb = partial + ((size_t)kc * B_ + b) * TILE_;

  float s = 0.f, dval = 0.f;
  const int di = c & 63;               // row-local index of diag for this col
  #pragma unroll
  for (int i = 0; i < 64; i++) {
    float v = gb[(rg * 64 + i) * N_ + c];
    s += v;
    if (i == di) dval = v;
  }
  for (int off = 32; off; off >>= 1) s += __shfl_down(s, off);
  if ((t & 63) == 0) red[t >> 6] = s;
  // diag: exactly one thread per column holds row==c
  if (rg == (c >> 6)) atomicAdd(&sq[b * N_ + c], dval);
  __syncthreads();
  if (t == 0) {
    float T = 0.f;
    #pragma unroll
    for (int i = 0; i < 16; i++) T += red[i];
    atomicAdd(&tot[b], T);
  }
}

// Sum 4 partials inline, reconstruct L2, 5-kernel exp with quadrant signs.
// 256 blocks (4 row-chunks x 64 batches) -> full CU utilization.
__global__ __launch_bounds__(1024, 4) void k_exp(
    const float* __restrict__ partial, const float* __restrict__ tot,
    const float* __restrict__ sq, float* __restrict__ out) {
  __shared__ float sqs[N_];
  __shared__ float red[16];
  __shared__ float bws;
  const int rc = blockIdx.x & 3;       // 64-row chunk
  const int b  = blockIdx.x >> 2;
  const int t  = threadIdx.x;          // 1024
  const int c  = t & 255;
  const int sg = t >> 8;               // 16-row subgroup

  if (t < N_) sqs[t] = sq[b * N_ + t];
  __syncthreads();
  if (t < N_) {
    float v = sqs[t];
    for (int off = 32; off; off >>= 1) v += __shfl_down(v, off);
    if ((t & 63) == 0) red[t >> 6] = v;
  }
  __syncthreads();
  if (t == 0) {
    float ssq = red[0] + red[1] + red[2] + red[3];
    float SL2 = 2.f * (float)N_ * ssq - 2.f * tot[b];
    bws = SL2 / (float)(N_ * N_ - N_) * 0.25f;  // / kernel_mul^(num//2)
  }
  __syncthreads();

  const float bwv = bws;
  float nb[5];
  #pragma unroll
  for (int k = 0; k < 5; k++)
    nb[k] = -1.4426950408889634f / (bwv * (float)(1 << k));
  const float sqc = sq ? sqs[c] : 0.f;
  const float sgn = ((rc < 2) == (c < S_)) ? 1.f : -1.f;  // quadrant sign

  const float* p0 = partial + (size_t)b * TILE_;
  float accv = 0.f;
  #pragma unroll 4
  for (int i = 0; i < 16; i++) {
    const int row = rc * 64 + sg * 16 + i;
    float g = p0[row * N_ + c]
            + p0[(size_t)1 * B_ * TILE_ + row * N_ + c]
            + p0[(size_t)2 * B_ * TILE_ + row * N_ + c]
            + p0[(size_t)3 * B_ * TILE_ + row * N_ + c];
    const float L2 = sqs[row] + sqc - 2.f * g;
    float s = 0.f;
    #pragma unroll
    for (int k = 0; k < 5; k++) s += exp2f(L2 * nb[k]);
    accv += s;
  }
  accv *= sgn;
  for (int off = 32; off; off >>= 1) accv += __shfl_down(accv, off);
  __syncthreads();  // red[] reuse safe
  if ((t & 63) == 0) red[t >> 6] = accv;
  __syncthreads();
  if (t == 0) {
    float s = 0.f;
    #pragma unroll
    for (int i = 0; i < 16; i++) s += red[i];
    atomicAdd(out, s * (1.0f / (64.f * 16384.f)));  // / (B * S*S)
  }
}

extern "C" void kernel_launch(void* const* d_in, const int* in_sizes, int n_in,
                              void* d_out, int out_size, void* d_ws, size_t ws_size,
                              hipStream_t stream) {
  const float* src = (const float*)d_in[0];
  const float* tgt = (const float*)d_in[1];
  const size_t partial_bytes = (size_t)KC_ * B_ * TILE_ * sizeof(float);  // 67 MB
  float* partial = (float*)d_ws;
  float* tot     = (float*)((char*)d_ws + partial_bytes);         // 64 floats
  float* sq      = tot + B_;                                      // 64*256 floats
  hipMemsetAsync(tot, 0, (B_ + B_ * N_) * sizeof(float), stream);
  hipMemsetAsync(d_out, 0, sizeof(float), stream);
  k_gram<<<dim3(KC_, B_), 1024, 0, stream>>>(src, tgt, partial);
  k_stat<<<KC_ * B_, 1024, 0, stream>>>(partial, tot, sq);
  k_exp<<<KC_ * B_, 1024, 0, stream>>>(partial, tot, sq, (float*)d_out);
}

// Round 4
// 311.634 us; speedup vs baseline: 1.1425x; 1.0195x over previous
//
#include <hip/hip_runtime.h>

#define B_  64
#define D_  4096
#define S_  128
#define N_  256
#define KC_ 4
#define KPB (D_ / KC_)     // 1024 K per kc slice
#define BK  32             // K per LDS chunk
#define NCH (KPB / BK)     // 32 chunks
#define RS  40             // LDS row stride (shorts): 32 data + 8 pad, 16B-aligned granules
#define LDSBUF (N_ * RS)   // 10240 shorts = 20 KB per buffer
#define TILE_ (N_ * N_)

using short8   = __attribute__((ext_vector_type(8)))  short;
using floatx16 = __attribute__((ext_vector_type(16))) float;

__device__ __forceinline__ unsigned int f2bf(float f) {
  unsigned int u = __builtin_bit_cast(unsigned int, f);
  return (u + 0x7FFFu + ((u >> 16) & 1u)) >> 16;   // round-to-nearest-even
}

// granule swizzle: rows r,r+8,r+16,r+24 share a bank phase (stride 20 dwords);
// XOR with (n>>3)&3 gives them distinct 4-bank groups -> worst case 2-way (free).
__device__ __forceinline__ int swz(int n, int g) {
  return n * RS + (((g ^ (n & 3) ^ ((n >> 3) & 3)) & 3) << 3);
}

// partial[kc][b][rows][cols], each block computes a 128x256 row-half.
// Also accumulates tot[b] (full-tile sum) and sq[b][c] (diagonal) via sparse atomics.
__global__ __launch_bounds__(512, 4) void k_gram(
    const float* __restrict__ src, const float* __restrict__ tgt,
    float* __restrict__ partial, float* __restrict__ tot,
    float* __restrict__ sq) {
  __shared__ unsigned short lds[2 * LDSBUF];  // 40 KB -> 2 blocks/CU
  __shared__ float red[8];
  const int bx  = blockIdx.x;
  const int kc  = bx >> 1;
  const int rh  = bx & 1;              // row half
  const int b   = blockIdx.y;
  const int tid = threadIdx.x;
  const int l   = tid & 63;
  const int w   = tid >> 6;            // wave 0..7
  const int tr  = w >> 2;              // 0..1 (64-row group within half)
  const int tc  = w & 3;               // 0..3 (64-col group)

  // staging: thread owns column n_s, granules g and g+2 (8 k each)
  const int n_s = tid & 255;
  const int g   = tid >> 8;            // 0..1
  const float* colbase = (n_s < S_)
      ? (src + (size_t)b * D_ * S_ + n_s)
      : (tgt + (size_t)b * D_ * S_ + (n_s - S_));
  const float* pA = colbase + (size_t)kc * KPB * S_;

  float ld[16];
  floatx16 acc[2][2];
  #pragma unroll
  for (int i = 0; i < 2; i++)
    #pragma unroll
    for (int j = 0; j < 2; j++)
      #pragma unroll
      for (int r = 0; r < 16; r++) acc[i][j][r] = 0.f;

  const int lm   = l & 31;
  const int lk   = l >> 5;             // 0/1
  const int ar   = rh * 128 + tr * 64 + lm;  // A rows (sub adds 32)
  const int bcol = tc * 64 + lm;             // B cols (sub adds 32)

  #define LOADCH(ch)                                                   \
    do {                                                               \
      const float* q = pA + (size_t)(ch) * BK * S_;                    \
      _Pragma("unroll")                                                \
      for (int j = 0; j < 8; j++) {                                    \
        ld[j]     = q[(size_t)(g * 8 + j) * S_];                       \
        ld[8 + j] = q[(size_t)((g + 2) * 8 + j) * S_];                 \
      }                                                                \
    } while (0)

  #define WRITECH(buf)                                                 \
    do {                                                               \
      uint4 wa, wb;                                                    \
      wa.x = f2bf(ld[0])  | (f2bf(ld[1])  << 16);                      \
      wa.y = f2bf(ld[2])  | (f2bf(ld[3])  << 16);                      \
      wa.z = f2bf(ld[4])  | (f2bf(ld[5])  << 16);                      \
      wa.w = f2bf(ld[6])  | (f2bf(ld[7])  << 16);                      \
      wb.x = f2bf(ld[8])  | (f2bf(ld[9])  << 16);                      \
      wb.y = f2bf(ld[10]) | (f2bf(ld[11]) << 16);                      \
      wb.z = f2bf(ld[12]) | (f2bf(ld[13]) << 16);                      \
      wb.w = f2bf(ld[14]) | (f2bf(ld[15]) << 16);                      \
      const int base = (buf) * LDSBUF;                                 \
      *(uint4*)&lds[base + swz(n_s, g)]     = wa;                      \
      *(uint4*)&lds[base + swz(n_s, g + 2)] = wb;                      \
    } while (0)

  #define MFMACH(buf)                                                  \
    do {                                                               \
      const unsigned short* L = &lds[(buf) * LDSBUF];                  \
      _Pragma("unroll")                                                \
      for (int ks = 0; ks < 2; ks++) {                                 \
        const int gg = ks * 2 + lk;                                    \
        short8 a0 = *(const short8*)&L[swz(ar,        gg)];            \
        short8 a1 = *(const short8*)&L[swz(ar + 32,   gg)];            \
        short8 b0 = *(const short8*)&L[swz(bcol,      gg)];            \
        short8 b1 = *(const short8*)&L[swz(bcol + 32, gg)];            \
        acc[0][0] = __builtin_amdgcn_mfma_f32_32x32x16_bf16(a0, b0, acc[0][0], 0, 0, 0); \
        acc[0][1] = __builtin_amdgcn_mfma_f32_32x32x16_bf16(a0, b1, acc[0][1], 0, 0, 0); \
        acc[1][0] = __builtin_amdgcn_mfma_f32_32x32x16_bf16(a1, b0, acc[1][0], 0, 0, 0); \
        acc[1][1] = __builtin_amdgcn_mfma_f32_32x32x16_bf16(a1, b1, acc[1][1], 0, 0, 0); \
      }                                                                \
    } while (0)

  LOADCH(0);
  WRITECH(0);
  __syncthreads();
  for (int ch = 0; ch < NCH - 1; ch++) {
    LOADCH(ch + 1);          // loads for next chunk fly during MFMA
    MFMACH(ch & 1);
    WRITECH((ch + 1) & 1);   // vmcnt wait lands here
    __syncthreads();
  }
  MFMACH((NCH - 1) & 1);

  // ---- epilogue: store partial half-tile (plain stores) ----
  float* gb = partial + ((size_t)kc * B_ + b) * TILE_;
  #pragma unroll
  for (int i = 0; i < 2; i++)
    #pragma unroll
    for (int j = 0; j < 2; j++)
      #pragma unroll
      for (int r = 0; r < 16; r++) {
        const int row = (r & 3) + 8 * (r >> 2) + 4 * lk;  // verified C/D layout
        const int nr  = rh * 128 + tr * 64 + i * 32 + row;
        const int nc  = tc * 64 + j * 32 + (l & 31);
        gb[nr * N_ + nc] = acc[i][j][r];
      }

  // ---- tot[b]: block-level sum of this partial half-tile ----
  float s = 0.f;
  #pragma unroll
  for (int i = 0; i < 2; i++)
    #pragma unroll
    for (int j = 0; j < 2; j++)
      #pragma unroll
      for (int r = 0; r < 16; r++) s += acc[i][j][r];
  for (int off = 32; off; off >>= 1) s += __shfl_down(s, off);
  if (l == 0) red[w] = s;
  __syncthreads();
  if (tid == 0) {
    float T = red[0] + red[1] + red[2] + red[3]
            + red[4] + red[5] + red[6] + red[7];
    atomicAdd(&tot[b], T);
  }

  // ---- sq[b][c]: diagonal contributions ----
  if ((rh * 2 + tr) == tc && lk == ((l >> 2) & 1)) {
    const int c = l & 31;
    const int r = (c >> 3) * 4 + (c & 3);   // reg holding row==col
    #pragma unroll
    for (int i = 0; i < 2; i++)
      atomicAdd(&sq[b * N_ + tc * 64 + i * 32 + c], acc[i][i][r]);
  }
  #undef LOADCH
  #undef WRITECH
  #undef MFMACH
}

// Sum 4 partials inline, reconstruct L2, 5-kernel exp with quadrant signs.
// 256 blocks (4 row-chunks x 64 batches) -> full CU coverage.
__global__ __launch_bounds__(1024, 2) void k_exp(
    const float* __restrict__ partial, const float* __restrict__ tot,
    const float* __restrict__ sq, float* __restrict__ out) {
  __shared__ float sqs[N_];
  __shared__ float red[16];
  __shared__ float bws;
  const int rc = blockIdx.x & 3;       // 64-row chunk
  const int b  = blockIdx.x >> 2;
  const int t  = threadIdx.x;          // 1024
  const int c  = t & 255;
  const int sg = t >> 8;               // 16-row subgroup

  if (t < N_) sqs[t] = sq[b * N_ + t];
  __syncthreads();
  if (t < N_) {
    float v = sqs[t];
    for (int off = 32; off; off >>= 1) v += __shfl_down(v, off);
    if ((t & 63) == 0) red[t >> 6] = v;
  }
  __syncthreads();
  if (t == 0) {
    float ssq = red[0] + red[1] + red[2] + red[3];
    float SL2 = 2.f * (float)N_ * ssq - 2.f * tot[b];
    bws = SL2 / (float)(N_ * N_ - N_) * 0.25f;  // / kernel_mul^(num//2)
  }
  __syncthreads();

  const float bwv = bws;
  float nb[5];
  #pragma unroll
  for (int k = 0; k < 5; k++)
    nb[k] = -1.4426950408889634f / (bwv * (float)(1 << k));
  const float sqc = sqs[c];
  const float sgn = ((rc < 2) == (c < S_)) ? 1.f : -1.f;  // quadrant sign

  const float* p0 = partial + (size_t)b * TILE_;
  float accv = 0.f;
  #pragma unroll 4
  for (int i = 0; i < 16; i++) {
    const int row = rc * 64 + sg * 16 + i;
    float gg = p0[row * N_ + c]
             + p0[(size_t)1 * B_ * TILE_ + row * N_ + c]
             + p0[(size_t)2 * B_ * TILE_ + row * N_ + c]
             + p0[(size_t)3 * B_ * TILE_ + row * N_ + c];
    const float L2 = sqs[row] + sqc - 2.f * gg;
    float s = 0.f;
    #pragma unroll
    for (int k = 0; k < 5; k++) s += exp2f(L2 * nb[k]);
    accv += s;
  }
  accv *= sgn;
  for (int off = 32; off; off >>= 1) accv += __shfl_down(accv, off);
  __syncthreads();  // red[] reuse safe
  if ((t & 63) == 0) red[t >> 6] = accv;
  __syncthreads();
  if (t == 0) {
    float s = 0.f;
    #pragma unroll
    for (int i = 0; i < 16; i++) s += red[i];
    atomicAdd(out, s * (1.0f / (64.f * 16384.f)));  // / (B * S*S)
  }
}

extern "C" void kernel_launch(void* const* d_in, const int* in_sizes, int n_in,
                              void* d_out, int out_size, void* d_ws, size_t ws_size,
                              hipStream_t stream) {
  const float* src = (const float*)d_in[0];
  const float* tgt = (const float*)d_in[1];
  const size_t partial_bytes = (size_t)KC_ * B_ * TILE_ * sizeof(float);  // 67 MB
  float* partial = (float*)d_ws;
  float* tot     = (float*)((char*)d_ws + partial_bytes);         // 64 floats
  float* sq      = tot + B_;                                      // 64*256 floats
  hipMemsetAsync(tot, 0, (B_ + B_ * N_) * sizeof(float), stream);
  hipMemsetAsync(d_out, 0, sizeof(float), stream);
  k_gram<<<dim3(KC_ * 2, B_), 512, 0, stream>>>(src, tgt, partial, tot, sq);
  k_exp<<<4 * B_, 1024, 0, stream>>>(partial, tot, sq, (float*)d_out);
}